// Round 3
// baseline (644.049 us; speedup 1.0000x reference)
//
#include <hip/hip_runtime.h>

// Problem constants (from reference): N=128, Cin=64, T=128, V=25, O=64, R=8
#define EPSV 1e-5f
constexpr int NN = 128, CIN = 64, TT = 128, VV = 25, OO = 64, RR = 8;
constexpr int TVQ   = TT * VV;        // 3200  (per-channel plane)
constexpr int XSAMP = CIN * TVQ;      // 204800 (per-sample x)
constexpr int YSAMP = OO * TT * VV;   // 819200 (per-sample y)
constexpr int RTV   = RR * TT * VV;   // 25600 (GroupNorm count)
constexpr int S12N  = 2 * RR * VV;    // 400   (s1+s2 per sample)
constexpr int YPAD  = 28;             // padded v for 16B-aligned y_sum rows
constexpr int YSUMP_SAMP = OO * VV * YPAD;  // 44800

// ---------------------------------------------------------------- zero scratch
__global__ __launch_bounds__(256) void kZero(float* __restrict__ p, int n)
{
    int i = blockIdx.x * 256 + threadIdx.x;
    if (i < n) p[i] = 0.f;
}

// ---------------------------------------------------------------- kernel A
// One pass over x. Per block: (n, t-chunk of 32). 200 threads own 4 consecutive
// (t,v) points each (float4 loads, coalesced). Outputs: s12g[n][400] =
// sum_t conv_pre_bias, ssqg[n][2] = sum of squares (bias included).
__global__ __launch_bounds__(256) void kA(const float* __restrict__ x,
    const float* __restrict__ w1, const float* __restrict__ b1,
    const float* __restrict__ w2, const float* __restrict__ b2,
    float* __restrict__ s12g, float* __restrict__ ssqg)
{
    __shared__ float wt1[CIN * RR], wt2[CIN * RR];   // transposed [c][r]
    __shared__ float s1l[RR * VV], s2l[RR * VV];
    __shared__ float redA[4], redB[4];
    const int tid = threadIdx.x;
    const int tc  = blockIdx.x;   // 0..3  (32 t each)
    const int n   = blockIdx.y;

    for (int e = tid; e < CIN * RR; e += 256) {
        int r = e >> 6, c = e & 63;
        wt1[c * RR + r] = w1[e];
        wt2[c * RR + r] = w2[e];
    }
    for (int e = tid; e < 2 * RR * VV; e += 256) {
        if (e < RR * VV) s1l[e] = 0.f; else s2l[e - RR * VV] = 0.f;
    }
    __syncthreads();

    float acc1[4][RR], acc2[4][RR];
    #pragma unroll
    for (int j = 0; j < 4; ++j)
        #pragma unroll
        for (int r = 0; r < RR; ++r) { acc1[j][r] = 0.f; acc2[j][r] = 0.f; }

    const bool active = (tid < 200);
    const int p0 = tid * 4;                       // flat (t,v) offset in chunk
    const float* xb = x + (size_t)n * XSAMP + tc * 800 + p0;
    if (active) {
        #pragma unroll 4
        for (int c = 0; c < CIN; ++c) {
            float4 xv  = *(const float4*)(xb + c * TVQ);
            float4 wa1 = *(const float4*)(&wt1[c * RR]);
            float4 wb1 = *(const float4*)(&wt1[c * RR + 4]);
            float4 wa2 = *(const float4*)(&wt2[c * RR]);
            float4 wb2 = *(const float4*)(&wt2[c * RR + 4]);
            float xj[4]  = {xv.x, xv.y, xv.z, xv.w};
            float w1v[8] = {wa1.x, wa1.y, wa1.z, wa1.w, wb1.x, wb1.y, wb1.z, wb1.w};
            float w2v[8] = {wa2.x, wa2.y, wa2.z, wa2.w, wb2.x, wb2.y, wb2.z, wb2.w};
            #pragma unroll
            for (int j = 0; j < 4; ++j)
                #pragma unroll
                for (int r = 0; r < RR; ++r) {
                    acc1[j][r] += w1v[r] * xj[j];
                    acc2[j][r] += w2v[r] * xj[j];
                }
        }
    }

    float b1r[RR], b2r[RR];
    #pragma unroll
    for (int r = 0; r < RR; ++r) { b1r[r] = b1[r]; b2r[r] = b2[r]; }

    float ssq1 = 0.f, ssq2 = 0.f;
    if (active) {
        #pragma unroll
        for (int j = 0; j < 4; ++j) {
            int v = (p0 + j) % VV;
            #pragma unroll
            for (int r = 0; r < RR; ++r) {
                float c1 = acc1[j][r] + b1r[r]; ssq1 += c1 * c1;
                float c2 = acc2[j][r] + b2r[r]; ssq2 += c2 * c2;
                atomicAdd(&s1l[r * VV + v], acc1[j][r]);
                atomicAdd(&s2l[r * VV + v], acc2[j][r]);
            }
        }
    }
    #pragma unroll
    for (int off = 32; off > 0; off >>= 1) {
        ssq1 += __shfl_down(ssq1, off);
        ssq2 += __shfl_down(ssq2, off);
    }
    if ((tid & 63) == 0) { redA[tid >> 6] = ssq1; redB[tid >> 6] = ssq2; }
    __syncthreads();                               // LDS atomics + redA/B done
    for (int e = tid; e < S12N; e += 256) {
        float pv = (e < RR * VV) ? s1l[e] : s2l[e - RR * VV];
        atomicAdd(&s12g[n * S12N + e], pv);
    }
    if (tid == 0) {
        atomicAdd(&ssqg[n * 2 + 0], redA[0] + redA[1] + redA[2] + redA[3]);
        atomicAdd(&ssqg[n * 2 + 1], redB[0] + redB[1] + redB[2] + redB[3]);
    }
}

// ---------------------------------------------------------------- kernel B
__device__ __forceinline__ float tanh_fast(float v)
{
    float e = __expf(2.f * v);
    return 1.f - 2.f / (e + 1.f);    // safe at +/-inf of e
}

// Grid (5, N): bx selects a 125-point chunk of the 625 (u,v) pairs (R2: was
// 1 block/sample = 0.5 block/CU -> starved). Each block redundantly finalizes
// the (cheap) GN stats, then emits its chunk of padded y_sum[n][o][u][28].
__global__ __launch_bounds__(512) void kB(
    const float* __restrict__ s12g, const float* __restrict__ ssqg,
    const float* __restrict__ b1, const float* __restrict__ g1, const float* __restrict__ be1,
    const float* __restrict__ b2, const float* __restrict__ g2, const float* __restrict__ be2,
    const float* __restrict__ Amat, const float* __restrict__ w4, const float* __restrict__ b4,
    float* __restrict__ ysump)
{
    __shared__ float x1g[RR * VV], x2g[RR * VV];
    __shared__ float w4l[OO * RR];
    __shared__ float b4l[OO];
    __shared__ float stats[2];
    __shared__ float mss[4];       // mu1, rs1, mu2, rs2
    const int tid = threadIdx.x;
    const int bx  = blockIdx.x;    // 0..4
    const int n   = blockIdx.y;

    if (tid < 2) stats[tid] = 0.f;
    if (tid < OO * RR) w4l[tid] = w4[tid];     // 512 threads, 512 entries
    if (tid < OO) b4l[tid] = b4[tid];
    __syncthreads();

    float sv = 0.f;
    if (tid < S12N) {
        sv = s12g[n * S12N + tid];
        atomicAdd(&stats[tid / (RR * VV)], sv);
    }
    __syncthreads();
    if (tid == 0) {
        float sb1 = 0.f, sb2 = 0.f;
        for (int r = 0; r < RR; ++r) { sb1 += b1[r]; sb2 += b2[r]; }
        float mu1 = (stats[0] + (float)(TT * VV) * sb1) / (float)RTV;
        float mu2 = (stats[1] + (float)(TT * VV) * sb2) / (float)RTV;
        float var1 = ssqg[n * 2 + 0] / (float)RTV - mu1 * mu1;
        float var2 = ssqg[n * 2 + 1] / (float)RTV - mu2 * mu2;
        mss[0] = mu1; mss[1] = rsqrtf(var1 + EPSV);
        mss[2] = mu2; mss[3] = rsqrtf(var2 + EPSV);
    }
    __syncthreads();
    if (tid < S12N) {
        int br = tid / (RR * VV);
        int i  = tid % (RR * VV);
        int r  = i / VV;
        float mu = mss[br * 2], rs = mss[br * 2 + 1];
        float mean_t = sv / (float)TT + (br ? b2[r] : b1[r]);
        float g  = br ? g2[r]  : g1[r];
        float be = br ? be2[r] : be1[r];
        float val = g * (mean_t - mu) * rs + be;
        if (br == 0) x1g[i] = val; else x2g[i] = val;
    }
    __syncthreads();

    float* yn = ysump + (size_t)n * YSUMP_SAMP;
    const int pend = (bx + 1) * 125;     // 5*125 = 625 exactly
    for (int p = bx * 125 + tid; p < pend; p += 512) {
        int u = p / VV, v = p % VV;
        float Av = Amat[p];
        float ys[RR];
        #pragma unroll
        for (int r = 0; r < RR; ++r) {
            float d = x1g[r * VV + u] - x1g[r * VV + v];
            float m = x2g[r * VV + u] * x2g[r * VV + v];
            ys[r] = tanh_fast(d) + tanh_fast(m) + Av;   // ALPHA = 1
        }
        for (int o = 0; o < OO; ++o) {
            float a = b4l[o];
            #pragma unroll
            for (int r = 0; r < RR; ++r) a += w4l[o * RR + r] * ys[r];
            yn[(o * VV + u) * YPAD + v] = a;
        }
    }
    // zero the v-pad cells (25..27) — once per sample (bx==0)
    if (bx == 0) {
        for (int q = tid; q < OO * VV * 3; q += 512) {
            int o = q / (VV * 3), rem = q % (VV * 3);
            int u = rem / 3, v = VV + rem % 3;
            yn[(o * VV + u) * YPAD + v] = 0.f;
        }
    }
}

// ---------------------------------------------------------------- kernel C
// R2 rewrite. 256 threads = 64 o x 4 th; each thread owns t = t0+2*th and
// t0+2*th+1 (two x3 rows in registers -> halves aggregation LDS reads/FMA).
// Phase 1: x tile [64c][8t][28] in LDS, broadcast b128 reads, w3 in register
// halves (NO launch_bounds reg cap — R2 bug: (512,4) forced 64 VGPRs ->
// spills, 60 MB excess FETCH). Phase 2: ysum staged in 4 u-chunks of 8 into
// the same LDS buffer with ROW STRIDE 225 (odd -> conflict-free lane-spread
// reads; R2 bug: stride 200 transpose = 16-way conflicts, 9.1M cycles).
// ~9 barriers/block instead of 50. Stores: each thread writes 2x25
// contiguous floats; a block covers 800 B contiguous runs per o -> L2 merges.
__global__ __launch_bounds__(256) void kC(
    const float* __restrict__ x, const float* __restrict__ w3,
    const float* __restrict__ b3, const float* __restrict__ ysump,
    float* __restrict__ y)
{
    __shared__ float lds[14400];         // 57.6 KB -> 2 blocks/CU
    const int tid = threadIdx.x;
    const int o   = tid & 63;
    const int th  = tid >> 6;            // 0..3
    const int tc  = blockIdx.x;          // 0..15
    const int n   = blockIdx.y;
    const int t0  = tc * 8;

    // stage x[n, :, t0:t0+8, :] -> lds[c*224 + t*28 + v]  (float4 global reads)
    const float* xn = x + (size_t)n * XSAMP + t0 * VV;
    for (int e4 = tid; e4 < CIN * 50; e4 += 256) {
        int c = e4 / 50, r4 = (e4 % 50) * 4;
        float4 tmp = *(const float4*)(xn + c * TVQ + r4);
        float tv[4] = {tmp.x, tmp.y, tmp.z, tmp.w};
        #pragma unroll
        for (int j = 0; j < 4; ++j) {
            int rem = r4 + j;
            lds[c * 224 + (rem / VV) * 28 + (rem % VV)] = tv[j];
        }
    }
    __syncthreads();

    float acc0[VV], acc1[VV];
    #pragma unroll
    for (int i = 0; i < VV; ++i) { acc0[i] = 0.f; acc1[i] = 0.f; }

    #pragma unroll 1
    for (int half = 0; half < 2; ++half) {
        float w3r[32];
        #pragma unroll
        for (int q = 0; q < 8; ++q) {
            float4 wv = *(const float4*)(w3 + o * CIN + half * 32 + q * 4);
            w3r[q*4+0] = wv.x; w3r[q*4+1] = wv.y; w3r[q*4+2] = wv.z; w3r[q*4+3] = wv.w;
        }
        #pragma unroll
        for (int ci = 0; ci < 32; ++ci) {
            const float w = w3r[ci];
            const float* p = &lds[(half * 32 + ci) * 224 + (2 * th) * 28];
            #pragma unroll
            for (int row = 0; row < 2; ++row) {
                float* a = row ? acc1 : acc0;
                const float* pr = p + row * 28;
                float4 a0 = *(const float4*)(pr + 0);
                float4 a1 = *(const float4*)(pr + 4);
                float4 a2 = *(const float4*)(pr + 8);
                float4 a3 = *(const float4*)(pr + 12);
                float4 a4 = *(const float4*)(pr + 16);
                float4 a5 = *(const float4*)(pr + 20);
                float  a6 = pr[24];
                a[0]  += w*a0.x; a[1]  += w*a0.y; a[2]  += w*a0.z; a[3]  += w*a0.w;
                a[4]  += w*a1.x; a[5]  += w*a1.y; a[6]  += w*a1.z; a[7]  += w*a1.w;
                a[8]  += w*a2.x; a[9]  += w*a2.y; a[10] += w*a2.z; a[11] += w*a2.w;
                a[12] += w*a3.x; a[13] += w*a3.y; a[14] += w*a3.z; a[15] += w*a3.w;
                a[16] += w*a4.x; a[17] += w*a4.y; a[18] += w*a4.z; a[19] += w*a4.w;
                a[20] += w*a5.x; a[21] += w*a5.y; a[22] += w*a5.z; a[23] += w*a5.w;
                a[24] += w*a6;
            }
        }
    }
    const float bias = b3[o];
    #pragma unroll
    for (int i = 0; i < VV; ++i) { acc0[i] += bias; acc1[i] += bias; }

    // phase 2: aggregation over u in 4 chunks of <=8
    const float* ysn = ysump + (size_t)n * YSUMP_SAMP;   // (o*25+u)*28+v
    float* yb = y + (size_t)n * YSAMP + (size_t)o * TVQ + t0 * VV;
    #pragma unroll 1
    for (int chunk = 0; chunk < 4; ++chunk) {
        const int u0 = chunk * 8;
        const int cs = (u0 + 8 <= VV) ? 8 : (VV - u0);   // 8,8,8,1
        __syncthreads();      // conv reads / previous chunk reads complete
        // stage ysum[o, u0:u0+cs, 0:28] -> lds[o*225 + uu*28 + v]
        for (int e4 = tid; e4 < 64 * cs * 7; e4 += 256) {
            int oo = e4 / (cs * 7), k4 = (e4 % (cs * 7)) * 4;
            float4 tmp = *(const float4*)(ysn + oo * 700 + u0 * 28 + k4);
            float* dst = &lds[oo * 225 + k4];
            dst[0] = tmp.x; dst[1] = tmp.y; dst[2] = tmp.z; dst[3] = tmp.w;
        }
        __syncthreads();
        #pragma unroll 1
        for (int uu = 0; uu < cs; ++uu) {
            const float* yr = &lds[o * 225 + uu * 28];
            float s0a = 0.f, s0b = 0.f, s1a = 0.f, s1b = 0.f;
            #pragma unroll
            for (int v = 0; v < 24; v += 2) {
                float ya = yr[v], yb2 = yr[v + 1];
                s0a += ya * acc0[v];     s0b += yb2 * acc0[v + 1];
                s1a += ya * acc1[v];     s1b += yb2 * acc1[v + 1];
            }
            float y24 = yr[24];
            s0a += y24 * acc0[24];
            s1a += y24 * acc1[24];
            const int u = u0 + uu;
            yb[(2 * th) * VV + u]     = s0a + s0b;
            yb[(2 * th + 1) * VV + u] = s1a + s1b;
        }
    }
}

// ---------------------------------------------------------------- launch
extern "C" void kernel_launch(void* const* d_in, const int* in_sizes, int n_in,
                              void* d_out, int out_size, void* d_ws, size_t ws_size,
                              hipStream_t stream)
{
    const float* x   = (const float*)d_in[0];
    const float* Am  = (const float*)d_in[1];
    const float* w1  = (const float*)d_in[2];
    const float* b1  = (const float*)d_in[3];
    const float* g1  = (const float*)d_in[4];
    const float* be1 = (const float*)d_in[5];
    const float* w2  = (const float*)d_in[6];
    const float* b2  = (const float*)d_in[7];
    const float* g2  = (const float*)d_in[8];
    const float* be2 = (const float*)d_in[9];
    const float* w3  = (const float*)d_in[10];
    const float* b3  = (const float*)d_in[11];
    const float* w4  = (const float*)d_in[12];
    const float* b4  = (const float*)d_in[13];
    float* y  = (float*)d_out;
    float* ws = (float*)d_ws;
    // workspace: s12g 128*400 | ssqg 128*2 | ysump 128*44800  (~23.1 MB total)
    float* s12g  = ws;
    float* ssqg  = ws + NN * S12N;
    float* ysump = ws + NN * S12N + NN * 2;

    const int nz = NN * S12N + NN * 2;
    hipLaunchKernelGGL(kZero, dim3((nz + 255) / 256), dim3(256), 0, stream, ws, nz);
    hipLaunchKernelGGL(kA, dim3(4, NN), dim3(256), 0, stream,
                       x, w1, b1, w2, b2, s12g, ssqg);
    hipLaunchKernelGGL(kB, dim3(5, NN), dim3(512), 0, stream,
                       s12g, ssqg, b1, g1, be1, b2, g2, be2, Am, w4, b4, ysump);
    hipLaunchKernelGGL(kC, dim3(16, NN), dim3(256), 0, stream,
                       x, w3, b3, ysump, y);
}

// Round 4
// 442.993 us; speedup vs baseline: 1.4539x; 1.4539x over previous
//
#include <hip/hip_runtime.h>

// Problem constants (from reference): N=128, Cin=64, T=128, V=25, O=64, R=8
#define EPSV 1e-5f
constexpr int NN = 128, CIN = 64, TT = 128, VV = 25, OO = 64, RR = 8;
constexpr int TVQ   = TT * VV;        // 3200  (per-channel plane)
constexpr int XSAMP = CIN * TVQ;      // 204800 (per-sample x)
constexpr int YSAMP = OO * TT * VV;   // 819200 (per-sample y)
constexpr int RTV   = RR * TT * VV;   // 25600 (GroupNorm count)
constexpr int S12N  = 2 * RR * VV;    // 400   (s1+s2 per sample)
constexpr int YST_SAMP = VV * VV * OO;  // 40000: ysumT[n][u][v][o]

// ---------------------------------------------------------------- zero scratch
__global__ __launch_bounds__(256) void kZero(float* __restrict__ p, int n)
{
    int i = blockIdx.x * 256 + threadIdx.x;
    if (i < n) p[i] = 0.f;
}

// ---------------------------------------------------------------- kernel A
// One pass over x. Per block: (n, t-chunk of 32). 200 threads own 4 consecutive
// (t,v) points each (float4 loads, coalesced). Outputs: s12g[n][400] =
// sum_t conv_pre_bias, ssqg[n][2] = sum of squares (bias included).
__global__ __launch_bounds__(256) void kA(const float* __restrict__ x,
    const float* __restrict__ w1, const float* __restrict__ b1,
    const float* __restrict__ w2, const float* __restrict__ b2,
    float* __restrict__ s12g, float* __restrict__ ssqg)
{
    __shared__ float wt1[CIN * RR], wt2[CIN * RR];   // transposed [c][r]
    __shared__ float s1l[RR * VV], s2l[RR * VV];
    __shared__ float redA[4], redB[4];
    const int tid = threadIdx.x;
    const int tc  = blockIdx.x;   // 0..3  (32 t each)
    const int n   = blockIdx.y;

    for (int e = tid; e < CIN * RR; e += 256) {
        int r = e >> 6, c = e & 63;
        wt1[c * RR + r] = w1[e];
        wt2[c * RR + r] = w2[e];
    }
    for (int e = tid; e < 2 * RR * VV; e += 256) {
        if (e < RR * VV) s1l[e] = 0.f; else s2l[e - RR * VV] = 0.f;
    }
    __syncthreads();

    float acc1[4][RR], acc2[4][RR];
    #pragma unroll
    for (int j = 0; j < 4; ++j)
        #pragma unroll
        for (int r = 0; r < RR; ++r) { acc1[j][r] = 0.f; acc2[j][r] = 0.f; }

    const bool active = (tid < 200);
    const int p0 = tid * 4;                       // flat (t,v) offset in chunk
    const float* xb = x + (size_t)n * XSAMP + tc * 800 + p0;
    if (active) {
        #pragma unroll 4
        for (int c = 0; c < CIN; ++c) {
            float4 xv  = *(const float4*)(xb + c * TVQ);
            float4 wa1 = *(const float4*)(&wt1[c * RR]);
            float4 wb1 = *(const float4*)(&wt1[c * RR + 4]);
            float4 wa2 = *(const float4*)(&wt2[c * RR]);
            float4 wb2 = *(const float4*)(&wt2[c * RR + 4]);
            float xj[4]  = {xv.x, xv.y, xv.z, xv.w};
            float w1v[8] = {wa1.x, wa1.y, wa1.z, wa1.w, wb1.x, wb1.y, wb1.z, wb1.w};
            float w2v[8] = {wa2.x, wa2.y, wa2.z, wa2.w, wb2.x, wb2.y, wb2.z, wb2.w};
            #pragma unroll
            for (int j = 0; j < 4; ++j)
                #pragma unroll
                for (int r = 0; r < RR; ++r) {
                    acc1[j][r] += w1v[r] * xj[j];
                    acc2[j][r] += w2v[r] * xj[j];
                }
        }
    }

    float b1r[RR], b2r[RR];
    #pragma unroll
    for (int r = 0; r < RR; ++r) { b1r[r] = b1[r]; b2r[r] = b2[r]; }

    float ssq1 = 0.f, ssq2 = 0.f;
    if (active) {
        #pragma unroll
        for (int j = 0; j < 4; ++j) {
            int v = (p0 + j) % VV;
            #pragma unroll
            for (int r = 0; r < RR; ++r) {
                float c1 = acc1[j][r] + b1r[r]; ssq1 += c1 * c1;
                float c2 = acc2[j][r] + b2r[r]; ssq2 += c2 * c2;
                atomicAdd(&s1l[r * VV + v], acc1[j][r]);
                atomicAdd(&s2l[r * VV + v], acc2[j][r]);
            }
        }
    }
    #pragma unroll
    for (int off = 32; off > 0; off >>= 1) {
        ssq1 += __shfl_down(ssq1, off);
        ssq2 += __shfl_down(ssq2, off);
    }
    if ((tid & 63) == 0) { redA[tid >> 6] = ssq1; redB[tid >> 6] = ssq2; }
    __syncthreads();                               // LDS atomics + redA/B done
    for (int e = tid; e < S12N; e += 256) {
        float pv = (e < RR * VV) ? s1l[e] : s2l[e - RR * VV];
        atomicAdd(&s12g[n * S12N + e], pv);
    }
    if (tid == 0) {
        atomicAdd(&ssqg[n * 2 + 0], redA[0] + redA[1] + redA[2] + redA[3]);
        atomicAdd(&ssqg[n * 2 + 1], redB[0] + redB[1] + redB[2] + redB[3]);
    }
}

// ---------------------------------------------------------------- kernel B
__device__ __forceinline__ float tanh_fast(float v)
{
    float e = __expf(2.f * v);
    return 1.f - 2.f / (e + 1.f);    // safe at +/-inf of e
}

// Grid (5, N): bx selects a 125-point chunk of the 625 (u,v) pairs. R4: output
// layout changed to ysumT[n][u][v][o] (o contiguous) so kC phase-2 reads are
// lane-coalesced; per-thread writes are 64 consecutive floats. No pad needed.
__global__ __launch_bounds__(512) void kB(
    const float* __restrict__ s12g, const float* __restrict__ ssqg,
    const float* __restrict__ b1, const float* __restrict__ g1, const float* __restrict__ be1,
    const float* __restrict__ b2, const float* __restrict__ g2, const float* __restrict__ be2,
    const float* __restrict__ Amat, const float* __restrict__ w4, const float* __restrict__ b4,
    float* __restrict__ ysumT)
{
    __shared__ float x1g[RR * VV], x2g[RR * VV];
    __shared__ float w4l[OO * RR];
    __shared__ float b4l[OO];
    __shared__ float stats[2];
    __shared__ float mss[4];       // mu1, rs1, mu2, rs2
    const int tid = threadIdx.x;
    const int bx  = blockIdx.x;    // 0..4
    const int n   = blockIdx.y;

    if (tid < 2) stats[tid] = 0.f;
    if (tid < OO * RR) w4l[tid] = w4[tid];     // 512 threads, 512 entries
    if (tid < OO) b4l[tid] = b4[tid];
    __syncthreads();

    float sv = 0.f;
    if (tid < S12N) {
        sv = s12g[n * S12N + tid];
        atomicAdd(&stats[tid / (RR * VV)], sv);
    }
    __syncthreads();
    if (tid == 0) {
        float sb1 = 0.f, sb2 = 0.f;
        for (int r = 0; r < RR; ++r) { sb1 += b1[r]; sb2 += b2[r]; }
        float mu1 = (stats[0] + (float)(TT * VV) * sb1) / (float)RTV;
        float mu2 = (stats[1] + (float)(TT * VV) * sb2) / (float)RTV;
        float var1 = ssqg[n * 2 + 0] / (float)RTV - mu1 * mu1;
        float var2 = ssqg[n * 2 + 1] / (float)RTV - mu2 * mu2;
        mss[0] = mu1; mss[1] = rsqrtf(var1 + EPSV);
        mss[2] = mu2; mss[3] = rsqrtf(var2 + EPSV);
    }
    __syncthreads();
    if (tid < S12N) {
        int br = tid / (RR * VV);
        int i  = tid % (RR * VV);
        int r  = i / VV;
        float mu = mss[br * 2], rs = mss[br * 2 + 1];
        float mean_t = sv / (float)TT + (br ? b2[r] : b1[r]);
        float g  = br ? g2[r]  : g1[r];
        float be = br ? be2[r] : be1[r];
        float val = g * (mean_t - mu) * rs + be;
        if (br == 0) x1g[i] = val; else x2g[i] = val;
    }
    __syncthreads();

    float* yn = ysumT + (size_t)n * YST_SAMP;
    const int pend = (bx + 1) * 125;     // 5*125 = 625 exactly
    for (int p = bx * 125 + tid; p < pend; p += 512) {
        int u = p / VV, v = p % VV;
        float Av = Amat[p];
        float ys[RR];
        #pragma unroll
        for (int r = 0; r < RR; ++r) {
            float d = x1g[r * VV + u] - x1g[r * VV + v];
            float m = x2g[r * VV + u] * x2g[r * VV + v];
            ys[r] = tanh_fast(d) + tanh_fast(m) + Av;   // ALPHA = 1
        }
        float* dst = yn + (size_t)p * OO;      // (u*25+v)*64, contiguous run
        for (int o = 0; o < OO; ++o) {
            float a = b4l[o];
            #pragma unroll
            for (int r = 0; r < RR; ++r) a += w4l[o * RR + r] * ys[r];
            dst[o] = a;
        }
    }
}

// ---------------------------------------------------------------- kernel C
// R4 rewrite. 256 threads, block=(n, t-chunk 8). LDS = one 28 KB buffer.
// Phase 1 (conv3): thread=(og 0..31, th 0..7) owns o={2og,2og+1}, t-row th.
//   x staged in two 32-channel passes [32c][8t][28v]; per c: 7 broadcast b128
//   reads serve 50 FMAs (halves R3's broadcast-read count). w3 in 16-c register
//   quarters.
// Transpose: x3 rows re-laid through LDS (stride 1601/25, conflict-free) into
//   o=lane layout: thread=(o2=tid&63, th2) owns t={2th2,2th2+1}, 2 half-rounds.
// Phase 2 (aggregation): ysumT[n][u][v][o] global reads are lane-consecutive
//   256B coalesced (L1/L2-hot, no LDS staging). Fully unrolled 25x25, 2 FMA
//   per load. Results res[2][25] in registers.
// Output: res -> LDS (o-stride 101, conflict-free) in 2 half-rounds -> lane-
//   consecutive coalesced b32 dump (contiguous 100-float runs per (o,half)).
__global__ __launch_bounds__(256) void kC(
    const float* __restrict__ x, const float* __restrict__ w3,
    const float* __restrict__ b3, const float* __restrict__ ysumT,
    float* __restrict__ y)
{
    __shared__ float lds[7168];          // 28672 B
    const int tid = threadIdx.x;
    const int tc  = blockIdx.x;          // 0..15
    const int n   = blockIdx.y;
    const int t0  = tc * 8;

    // ---------------- phase 1: conv3 ----------------
    const int og = tid >> 3;             // 0..31
    const int th = tid & 7;              // 0..7 (t-row)
    const int o0 = og * 2;

    float acc[2][VV];
    #pragma unroll
    for (int j = 0; j < 2; ++j)
        #pragma unroll
        for (int v = 0; v < VV; ++v) acc[j][v] = 0.f;

    const float* xn = x + (size_t)n * XSAMP + t0 * VV;
    #pragma unroll 1
    for (int cpass = 0; cpass < 2; ++cpass) {
        __syncthreads();                 // prior-pass reads done (no-op pass 0)
        for (int e4 = tid; e4 < 32 * 50; e4 += 256) {
            int cl = e4 / 50, r4 = (e4 % 50) * 4;
            float4 tv = *(const float4*)(xn + (cpass * 32 + cl) * TVQ + r4);
            float a[4] = {tv.x, tv.y, tv.z, tv.w};
            #pragma unroll
            for (int j = 0; j < 4; ++j) {
                int rem = r4 + j;
                lds[cl * 224 + (rem / VV) * 28 + (rem % VV)] = a[j];
            }
        }
        __syncthreads();
        #pragma unroll 1
        for (int q = 0; q < 2; ++q) {
            float w3q[2][16];
            #pragma unroll
            for (int j = 0; j < 2; ++j)
                #pragma unroll
                for (int k4 = 0; k4 < 4; ++k4) {
                    float4 wv = *(const float4*)(w3 + (o0 + j) * CIN
                                                 + cpass * 32 + q * 16 + k4 * 4);
                    w3q[j][k4*4+0] = wv.x; w3q[j][k4*4+1] = wv.y;
                    w3q[j][k4*4+2] = wv.z; w3q[j][k4*4+3] = wv.w;
                }
            #pragma unroll
            for (int ci = 0; ci < 16; ++ci) {
                const float* p = &lds[(q * 16 + ci) * 224 + th * 28];
                float4 a0 = *(const float4*)(p + 0);
                float4 a1 = *(const float4*)(p + 4);
                float4 a2 = *(const float4*)(p + 8);
                float4 a3 = *(const float4*)(p + 12);
                float4 a4 = *(const float4*)(p + 16);
                float4 a5 = *(const float4*)(p + 20);
                float  a6 = p[24];
                #pragma unroll
                for (int j = 0; j < 2; ++j) {
                    const float w = w3q[j][ci];
                    float* a = acc[j];
                    a[0]  += w*a0.x; a[1]  += w*a0.y; a[2]  += w*a0.z; a[3]  += w*a0.w;
                    a[4]  += w*a1.x; a[5]  += w*a1.y; a[6]  += w*a1.z; a[7]  += w*a1.w;
                    a[8]  += w*a2.x; a[9]  += w*a2.y; a[10] += w*a2.z; a[11] += w*a2.w;
                    a[12] += w*a3.x; a[13] += w*a3.y; a[14] += w*a3.z; a[15] += w*a3.w;
                    a[16] += w*a4.x; a[17] += w*a4.y; a[18] += w*a4.z; a[19] += w*a4.w;
                    a[20] += w*a5.x; a[21] += w*a5.y; a[22] += w*a5.z; a[23] += w*a5.w;
                    a[24] += w*a6;
                }
            }
        }
    }

    // ---------------- transpose x3 to o=lane layout ----------------
    const int o2  = tid & 63;
    const int th2 = tid >> 6;            // 0..3, owns t = {2*th2, 2*th2+1}
    const float bias = b3[o2];
    float acc2[2][VV];

    #pragma unroll 1
    for (int half = 0; half < 2; ++half) {
        __syncthreads();
        if ((th >> 2) == half) {         // this thread's t-row is in this half
            const int tl = th & 3;
            #pragma unroll
            for (int j = 0; j < 2; ++j)
                #pragma unroll
                for (int v = 0; v < VV; ++v)
                    lds[tl * 1601 + (o0 + j) * VV + v] = acc[j][v];
        }
        __syncthreads();
        if ((th2 >> 1) == half) {
            #pragma unroll
            for (int row = 0; row < 2; ++row) {
                const int tl = (2 * th2 + row) & 3;
                #pragma unroll
                for (int v = 0; v < VV; ++v)
                    acc2[row][v] = lds[tl * 1601 + o2 * VV + v];
            }
        }
    }
    #pragma unroll
    for (int row = 0; row < 2; ++row)
        #pragma unroll
        for (int v = 0; v < VV; ++v) acc2[row][v] += bias;

    // ---------------- phase 2: aggregation (global coalesced reads) --------
    const float* yT = ysumT + (size_t)n * YST_SAMP + o2;
    float res[2][VV];
    #pragma unroll
    for (int u = 0; u < VV; ++u) {
        float r0 = 0.f, r1 = 0.f;
        #pragma unroll
        for (int v = 0; v < VV; ++v) {
            float yv = yT[(u * VV + v) * OO];
            r0 += yv * acc2[0][v];
            r1 += yv * acc2[1][v];
        }
        res[0][u] = r0;
        res[1][u] = r1;
    }

    // ---------------- output: 2 half-round transposed coalesced dump ------
    float* yb = y + (size_t)n * YSAMP + t0 * VV;
    #pragma unroll 1
    for (int half = 0; half < 2; ++half) {
        __syncthreads();
        if ((th2 >> 1) == half) {
            #pragma unroll
            for (int row = 0; row < 2; ++row) {
                const int tl = (2 * th2 + row) & 3;
                #pragma unroll
                for (int u = 0; u < VV; ++u)
                    lds[o2 * 101 + tl * VV + u] = res[row][u];
            }
        }
        __syncthreads();
        for (int e = tid; e < 6400; e += 256) {
            int o = e / 100, m = e % 100;
            yb[o * TVQ + half * 100 + m] = lds[o * 101 + m];
        }
    }
}

// ---------------------------------------------------------------- launch
extern "C" void kernel_launch(void* const* d_in, const int* in_sizes, int n_in,
                              void* d_out, int out_size, void* d_ws, size_t ws_size,
                              hipStream_t stream)
{
    const float* x   = (const float*)d_in[0];
    const float* Am  = (const float*)d_in[1];
    const float* w1  = (const float*)d_in[2];
    const float* b1  = (const float*)d_in[3];
    const float* g1  = (const float*)d_in[4];
    const float* be1 = (const float*)d_in[5];
    const float* w2  = (const float*)d_in[6];
    const float* b2  = (const float*)d_in[7];
    const float* g2  = (const float*)d_in[8];
    const float* be2 = (const float*)d_in[9];
    const float* w3  = (const float*)d_in[10];
    const float* b3  = (const float*)d_in[11];
    const float* w4  = (const float*)d_in[12];
    const float* b4  = (const float*)d_in[13];
    float* y  = (float*)d_out;
    float* ws = (float*)d_ws;
    // workspace: s12g 128*400 | ssqg 128*2 | ysumT 128*40000  (~20.7 MB total)
    float* s12g  = ws;
    float* ssqg  = ws + NN * S12N;
    float* ysumT = ws + NN * S12N + NN * 2;

    const int nz = NN * S12N + NN * 2;
    hipLaunchKernelGGL(kZero, dim3((nz + 255) / 256), dim3(256), 0, stream, ws, nz);
    hipLaunchKernelGGL(kA, dim3(4, NN), dim3(256), 0, stream,
                       x, w1, b1, w2, b2, s12g, ssqg);
    hipLaunchKernelGGL(kB, dim3(5, NN), dim3(512), 0, stream,
                       s12g, ssqg, b1, g1, be1, b2, g2, be2, Am, w4, b4, ysumT);
    hipLaunchKernelGGL(kC, dim3(16, NN), dim3(256), 0, stream,
                       x, w3, b3, ysumT, y);
}